// Round 1
// baseline (32.309 us; speedup 1.0000x reference)
//
#include <hip/hip_runtime.h>

// RelationalAttentionContextEncoder2 — wave-per-batch, packed-f16, pre-scaled 1/15.
// v(i,j,h)/15 = a'(i,h) + c'(j,h) + w8'(h)*dist(i,j)   (all coeffs pre-scaled by 1/15)
// rel[i,h] = sum_{j != i} relu(v')      (diagonal skipped at compile time)
// prop[i,h] = relu(wp0*ei2 + wp1*ei3 + bp)   (unscaled, f32)
//
// v2 changes vs v1 (31.2 us):
//  - ai2[16] / c2[16] / prop all precomputed in ONE setup pass over entities
//    (uniform float4 loads of the ctx row); prop stored immediately.
//    -> all f32 weight/coeff registers are dead before the hot loop.
//  - hot loop is pure pk-f16: 4 uniform ds_read_b128 + 60 pk ops + 1 store per i.
//  - __launch_bounds__(256, 4): force >=4 waves/EU (VGPR <= 128). v1 was
//    suspected >128 VGPR -> 2 waves/SIMD -> ~34% issue efficiency.

constexpr int NE = 16;
constexpr int HH = 128;

typedef _Float16 h2 __attribute__((ext_vector_type(2)));
typedef float vf2 __attribute__((ext_vector_type(2)));   // native vec for nt-store

struct f2 { float x, y; };
__device__ __forceinline__ f2 add2(f2 a, f2 b) { return {a.x + b.x, a.y + b.y}; }
__device__ __forceinline__ f2 sub2(f2 a, f2 b) { return {a.x - b.x, a.y - b.y}; }
__device__ __forceinline__ f2 fma2s(f2 w, float s, f2 c) {
    return {fmaf(w.x, s, c.x), fmaf(w.y, s, c.y)};
}
__device__ __forceinline__ f2 mul2s(f2 a, float s) { return {a.x * s, a.y * s}; }
__device__ __forceinline__ f2 relu2(f2 a) { return {fmaxf(a.x, 0.f), fmaxf(a.y, 0.f)}; }
__device__ __forceinline__ h2 mk_h2(float x, float y) {
    h2 r; r.x = (_Float16)x; r.y = (_Float16)y; return r;
}

__global__ __launch_bounds__(256, 4) void relctx_kernel(
    const float* __restrict__ ctx,     // [B, 64]
    const float* __restrict__ W_rel,   // [9, 128]
    const float* __restrict__ b_rel,   // [128]
    const float* __restrict__ W_prop,  // [2, 128]
    const float* __restrict__ b_prop,  // [128]
    float* __restrict__ out,           // [B, 16, 256]
    int B)
{
    // per-wave dist table: f16 splat per (i,j), packed 4 j's per uint4
    __shared__ uint4 s_d2[4][NE][NE / 4];

    const int tid = threadIdx.x;
    const int wave = __builtin_amdgcn_readfirstlane(tid >> 6);  // scalar wave id
    const int lane = tid & 63;
    const int b = blockIdx.x * 4 + wave;
    if (b >= B) return;

    const float* __restrict__ cb = ctx + (size_t)b * (NE * 4);  // uniform base

    // ---- Phase 1: dist table. lane -> i = lane>>2, j-quad = lane&3 (covers all 16x4)
    {
        const int i = lane >> 2;
        const int jq = lane & 3;
        const float eix = cb[i * 4 + 0];
        const float eiy = cb[i * 4 + 1];
        unsigned q[4];
        #pragma unroll
        for (int t = 0; t < 4; ++t) {
            const int j = jq * 4 + t;
            const float dx = eix - cb[j * 4 + 0];
            const float dy = eiy - cb[j * 4 + 1];
            const float dist = sqrtf(fmaf(dx, dx, dy * dy));  // diag value unused
            q[t] = __builtin_bit_cast(unsigned, mk_h2(dist, dist));
        }
        s_d2[wave][i][jq] = make_uint4(q[0], q[1], q[2], q[3]);
    }
    // table is wave-private: same-wave LDS ordering only, no block barrier
    asm volatile("s_waitcnt lgkmcnt(0)" ::: "memory");

    // ---- Phase 2: weights (h-pair per lane), pre-scaled by 1/15
    const f2* W2 = (const f2*)W_rel;   // [9][64]
    const f2 w0 = W2[0 * 64 + lane];
    const f2 w1 = W2[1 * 64 + lane];
    const f2 w2 = W2[2 * 64 + lane];
    const f2 w3 = W2[3 * 64 + lane];
    const f2 w4 = W2[4 * 64 + lane];
    const f2 w5 = W2[5 * 64 + lane];
    const f2 w6 = W2[6 * 64 + lane];
    const f2 w7 = W2[7 * 64 + lane];
    const f2 w8 = W2[8 * 64 + lane];
    const f2 br  = ((const f2*)b_rel)[lane];
    const f2 wp0 = ((const f2*)W_prop)[lane];
    const f2 wp1 = ((const f2*)W_prop)[64 + lane];
    const f2 bp  = ((const f2*)b_prop)[lane];

    constexpr float S = 1.0f / 15.0f;
    const f2 u2s = mul2s(sub2(w2, w6), S);   // c' coeff of ej2
    const f2 u3s = mul2s(sub2(w3, w7), S);   // c' coeff of ej3
    const f2 t0s = mul2s(add2(w0, w6), S);   // a' coeff of ei2
    const f2 t1s = mul2s(add2(w1, w7), S);   // a' coeff of ei3
    const f2 w4s = mul2s(w4, S);
    const f2 w5s = mul2s(w5, S);
    const f2 brs = mul2s(br, S);
    const h2 w8h = mk_h2(w8.x * S, w8.y * S);
    const h2 hz = mk_h2(0.0f, 0.0f);

    // ---- Phase 2b: ONE pass over entities: c2[e], ai2[e] (f16), prop store.
    // After this loop every f32 coeff/weight register is dead -> low hot-loop VGPR.
    h2 c2[NE];
    h2 ai2[NE];
    const float4* __restrict__ cb4 = (const float4*)cb;   // uniform 16B loads
    float* __restrict__ ob = out + (size_t)b * NE * (2 * HH) + 2 * lane;
    #pragma unroll
    for (int e = 0; e < NE; ++e) {
        const float4 ev = cb4[e];   // x,y,z,w = ent[e][0..3]
        // c'(e) — identical formula/order to v1 for identical rounding
        f2 t = fma2s(u3s, ev.w, mul2s(u2s, ev.z));
        t = fma2s(w4s, -ev.x, t);
        t = fma2s(w5s, -ev.y, t);
        c2[e] = mk_h2(t.x, t.y);
        // a'(e)
        f2 ai = fma2s(t0s, ev.z, brs);
        ai = fma2s(t1s, ev.w, ai);
        ai = fma2s(w4s, ev.x, ai);
        ai = fma2s(w5s, ev.y, ai);
        ai2[e] = mk_h2(ai.x, ai.y);
        // prop(e) — store now, free wp0/wp1/bp before the hot loop
        const f2 prop = relu2(fma2s(wp0, ev.z, fma2s(wp1, ev.w, bp)));
        vf2 pv; pv.x = prop.x; pv.y = prop.y;
        __builtin_nontemporal_store(pv, (vf2*)(ob + (size_t)e * (2 * HH)));
    }

    // ---- Phase 3: all 16 i rows — pure pk-f16 hot loop
    #pragma unroll
    for (int i = 0; i < NE; ++i) {
        const h2 a = ai2[i];

        h2 a0 = hz, a1 = hz, a2 = hz, a3 = hz;
        #pragma unroll
        for (int jq = 0; jq < 4; ++jq) {
            const uint4 q = s_d2[wave][i][jq];   // uniform addr -> broadcast b128
            const unsigned qa[4] = {q.x, q.y, q.z, q.w};
            #pragma unroll
            for (int t = 0; t < 4; ++t) {
                const int j = jq * 4 + t;
                if (j == i) continue;            // compile-time diagonal skip
                const h2 d2 = __builtin_bit_cast(h2, qa[t]);
                h2 v = w8h * d2 + (a + c2[j]);        // v_pk_add + v_pk_fma
                v = __builtin_elementwise_max(v, hz); // v_pk_max_f16
                if (t == 0) a0 += v;
                else if (t == 1) a1 += v;
                else if (t == 2) a2 += v;
                else a3 += v;
            }
        }
        const h2 s = (a0 + a1) + (a2 + a3);     // 3 pk adds; already /15-scaled
        vf2 rv; rv.x = (float)s.x; rv.y = (float)s.y;
        __builtin_nontemporal_store(rv, (vf2*)(ob + (size_t)i * (2 * HH) + HH));
    }
}

extern "C" void kernel_launch(void* const* d_in, const int* in_sizes, int n_in,
                              void* d_out, int out_size, void* d_ws, size_t ws_size,
                              hipStream_t stream) {
    const float* ctx    = (const float*)d_in[0];
    const float* W_rel  = (const float*)d_in[1];
    const float* b_rel  = (const float*)d_in[2];
    const float* W_prop = (const float*)d_in[3];
    const float* b_prop = (const float*)d_in[4];
    float* out = (float*)d_out;

    const int B = in_sizes[0] / (NE * 4);
    const int grid = (B + 3) / 4;
    relctx_kernel<<<grid, 256, 0, stream>>>(ctx, W_rel, b_rel, W_prop, b_prop, out, B);
}

// Round 2
// 31.856 us; speedup vs baseline: 1.0142x; 1.0142x over previous
//
#include <hip/hip_runtime.h>

// RelationalAttentionContextEncoder2 — wave-per-batch, packed-f16, pre-scaled 1/15.
// v(i,j,h)/15 = a'(i,h) + c'(j,h) + w8'(h)*dist(i,j)   (all coeffs pre-scaled by 1/15)
// rel[i,h] = sum_{j != i} relu(v')      (diagonal skipped at compile time)
// prop[i,h] = relu(wp0*ei2 + wp1*ei3 + bp)   (unscaled, f32)
//
// v3 change vs v2 (32.3 us) / v1 (31.2 us):
//  - PLAIN stores instead of __builtin_nontemporal_store. Output is 134 MB,
//    which FITS in the 256 MB Infinity Cache. nt-stores forced a synchronous
//    drain to HBM at ~4.3 TB/s inside the kernel (write floor ~21 us, additive
//    with ~11 us of VALU). Plain stores land in L2/L3 at cache-write BW; the
//    HBM writeback happens after kernel end, off the measured critical path.

constexpr int NE = 16;
constexpr int HH = 128;

typedef _Float16 h2 __attribute__((ext_vector_type(2)));
typedef float vf2 __attribute__((ext_vector_type(2)));

struct f2 { float x, y; };
__device__ __forceinline__ f2 add2(f2 a, f2 b) { return {a.x + b.x, a.y + b.y}; }
__device__ __forceinline__ f2 sub2(f2 a, f2 b) { return {a.x - b.x, a.y - b.y}; }
__device__ __forceinline__ f2 fma2s(f2 w, float s, f2 c) {
    return {fmaf(w.x, s, c.x), fmaf(w.y, s, c.y)};
}
__device__ __forceinline__ f2 mul2s(f2 a, float s) { return {a.x * s, a.y * s}; }
__device__ __forceinline__ f2 relu2(f2 a) { return {fmaxf(a.x, 0.f), fmaxf(a.y, 0.f)}; }
__device__ __forceinline__ h2 mk_h2(float x, float y) {
    h2 r; r.x = (_Float16)x; r.y = (_Float16)y; return r;
}

__global__ __launch_bounds__(256, 4) void relctx_kernel(
    const float* __restrict__ ctx,     // [B, 64]
    const float* __restrict__ W_rel,   // [9, 128]
    const float* __restrict__ b_rel,   // [128]
    const float* __restrict__ W_prop,  // [2, 128]
    const float* __restrict__ b_prop,  // [128]
    float* __restrict__ out,           // [B, 16, 256]
    int B)
{
    // per-wave dist table: f16 splat per (i,j), packed 4 j's per uint4
    __shared__ uint4 s_d2[4][NE][NE / 4];

    const int tid = threadIdx.x;
    const int wave = __builtin_amdgcn_readfirstlane(tid >> 6);  // scalar wave id
    const int lane = tid & 63;
    const int b = blockIdx.x * 4 + wave;
    if (b >= B) return;

    const float* __restrict__ cb = ctx + (size_t)b * (NE * 4);  // uniform base

    // ---- Phase 1: dist table. lane -> i = lane>>2, j-quad = lane&3 (covers all 16x4)
    {
        const int i = lane >> 2;
        const int jq = lane & 3;
        const float eix = cb[i * 4 + 0];
        const float eiy = cb[i * 4 + 1];
        unsigned q[4];
        #pragma unroll
        for (int t = 0; t < 4; ++t) {
            const int j = jq * 4 + t;
            const float dx = eix - cb[j * 4 + 0];
            const float dy = eiy - cb[j * 4 + 1];
            const float dist = sqrtf(fmaf(dx, dx, dy * dy));  // diag value unused
            q[t] = __builtin_bit_cast(unsigned, mk_h2(dist, dist));
        }
        s_d2[wave][i][jq] = make_uint4(q[0], q[1], q[2], q[3]);
    }
    // table is wave-private: same-wave LDS ordering only, no block barrier
    asm volatile("s_waitcnt lgkmcnt(0)" ::: "memory");

    // ---- Phase 2: weights (h-pair per lane), pre-scaled by 1/15
    const f2* W2 = (const f2*)W_rel;   // [9][64]
    const f2 w0 = W2[0 * 64 + lane];
    const f2 w1 = W2[1 * 64 + lane];
    const f2 w2 = W2[2 * 64 + lane];
    const f2 w3 = W2[3 * 64 + lane];
    const f2 w4 = W2[4 * 64 + lane];
    const f2 w5 = W2[5 * 64 + lane];
    const f2 w6 = W2[6 * 64 + lane];
    const f2 w7 = W2[7 * 64 + lane];
    const f2 w8 = W2[8 * 64 + lane];
    const f2 br  = ((const f2*)b_rel)[lane];
    const f2 wp0 = ((const f2*)W_prop)[lane];
    const f2 wp1 = ((const f2*)W_prop)[64 + lane];
    const f2 bp  = ((const f2*)b_prop)[lane];

    constexpr float S = 1.0f / 15.0f;
    const f2 u2s = mul2s(sub2(w2, w6), S);   // c' coeff of ej2
    const f2 u3s = mul2s(sub2(w3, w7), S);   // c' coeff of ej3
    const f2 t0s = mul2s(add2(w0, w6), S);   // a' coeff of ei2
    const f2 t1s = mul2s(add2(w1, w7), S);   // a' coeff of ei3
    const f2 w4s = mul2s(w4, S);
    const f2 w5s = mul2s(w5, S);
    const f2 brs = mul2s(br, S);
    const h2 w8h = mk_h2(w8.x * S, w8.y * S);
    const h2 hz = mk_h2(0.0f, 0.0f);

    // ---- Phase 2b: ONE pass over entities: c2[e], ai2[e] (f16), prop store.
    h2 c2[NE];
    h2 ai2[NE];
    const float4* __restrict__ cb4 = (const float4*)cb;   // uniform 16B loads
    float* __restrict__ ob = out + (size_t)b * NE * (2 * HH) + 2 * lane;
    #pragma unroll
    for (int e = 0; e < NE; ++e) {
        const float4 ev = cb4[e];   // x,y,z,w = ent[e][0..3]
        // c'(e)
        f2 t = fma2s(u3s, ev.w, mul2s(u2s, ev.z));
        t = fma2s(w4s, -ev.x, t);
        t = fma2s(w5s, -ev.y, t);
        c2[e] = mk_h2(t.x, t.y);
        // a'(e)
        f2 ai = fma2s(t0s, ev.z, brs);
        ai = fma2s(t1s, ev.w, ai);
        ai = fma2s(w4s, ev.x, ai);
        ai = fma2s(w5s, ev.y, ai);
        ai2[e] = mk_h2(ai.x, ai.y);
        // prop(e) — store now (plain store: lands in L2/L3, writeback deferred)
        const f2 prop = relu2(fma2s(wp0, ev.z, fma2s(wp1, ev.w, bp)));
        vf2 pv; pv.x = prop.x; pv.y = prop.y;
        *(vf2*)(ob + (size_t)e * (2 * HH)) = pv;
    }

    // ---- Phase 3: all 16 i rows — pure pk-f16 hot loop
    #pragma unroll
    for (int i = 0; i < NE; ++i) {
        const h2 a = ai2[i];

        h2 a0 = hz, a1 = hz, a2 = hz, a3 = hz;
        #pragma unroll
        for (int jq = 0; jq < 4; ++jq) {
            const uint4 q = s_d2[wave][i][jq];   // uniform addr -> broadcast b128
            const unsigned qa[4] = {q.x, q.y, q.z, q.w};
            #pragma unroll
            for (int t = 0; t < 4; ++t) {
                const int j = jq * 4 + t;
                if (j == i) continue;            // compile-time diagonal skip
                const h2 d2 = __builtin_bit_cast(h2, qa[t]);
                h2 v = w8h * d2 + (a + c2[j]);        // v_pk_add + v_pk_fma
                v = __builtin_elementwise_max(v, hz); // v_pk_max_f16
                if (t == 0) a0 += v;
                else if (t == 1) a1 += v;
                else if (t == 2) a2 += v;
                else a3 += v;
            }
        }
        const h2 s = (a0 + a1) + (a2 + a3);     // already /15-scaled
        vf2 rv; rv.x = (float)s.x; rv.y = (float)s.y;
        *(vf2*)(ob + (size_t)i * (2 * HH) + HH) = rv;
    }
}

extern "C" void kernel_launch(void* const* d_in, const int* in_sizes, int n_in,
                              void* d_out, int out_size, void* d_ws, size_t ws_size,
                              hipStream_t stream) {
    const float* ctx    = (const float*)d_in[0];
    const float* W_rel  = (const float*)d_in[1];
    const float* b_rel  = (const float*)d_in[2];
    const float* W_prop = (const float*)d_in[3];
    const float* b_prop = (const float*)d_in[4];
    float* out = (float*)d_out;

    const int B = in_sizes[0] / (NE * 4);
    const int grid = (B + 3) / 4;
    relctx_kernel<<<grid, 256, 0, stream>>>(ctx, W_rel, b_rel, W_prop, b_prop, out, B);
}